// Round 1
// baseline (99.844 us; speedup 1.0000x reference)
//
#include <hip/hip_runtime.h>
#include <math.h>

#define TKEPS 1e-7f
#define NEG_INF (-__builtin_inff())

// Insert x into sorted-descending (t0>=t1>=...>=t5) top-6 list. Static
// indices only -> stays in VGPRs (no scratch).
__device__ __forceinline__ void ins6(float x, float& t0, float& t1, float& t2,
                                     float& t3, float& t4, float& t5) {
    float a = x, m;
    m = fmaxf(t0, a); a = fminf(t0, a); t0 = m;
    m = fmaxf(t1, a); a = fminf(t1, a); t1 = m;
    m = fmaxf(t2, a); a = fminf(t2, a); t2 = m;
    m = fmaxf(t3, a); a = fminf(t3, a); t3 = m;
    m = fmaxf(t4, a); a = fminf(t4, a); t4 = m;
    t5 = fmaxf(t5, a);
}

// Merge this lane's sorted-desc top-6 with partner lane's (xor mask),
// keeping top-6 of the union. Exact merge (tie-correct):
//   m_i = max over j+l=i+1, j,l>=0 of min(a_{j-1}, b_{l-1}), sentinel +inf.
__device__ __forceinline__ void merge6(int mask, float& a0, float& a1, float& a2,
                                       float& a3, float& a4, float& a5) {
    float b0 = __shfl_xor(a0, mask, 64);
    float b1 = __shfl_xor(a1, mask, 64);
    float b2 = __shfl_xor(a2, mask, 64);
    float b3 = __shfl_xor(a3, mask, 64);
    float b4 = __shfl_xor(a4, mask, 64);
    float b5 = __shfl_xor(a5, mask, 64);

    float m0 = fmaxf(a0, b0);
    float m1 = fmaxf(fmaxf(b1, fminf(a0, b0)), a1);
    float m2 = fmaxf(fmaxf(b2, fminf(a0, b1)),
                     fmaxf(fminf(a1, b0), a2));
    float m3 = fmaxf(fmaxf(fmaxf(b3, fminf(a0, b2)), fminf(a1, b1)),
                     fmaxf(fminf(a2, b0), a3));
    float m4 = fmaxf(fmaxf(fmaxf(b4, fminf(a0, b3)), fminf(a1, b2)),
                     fmaxf(fmaxf(fminf(a2, b1), fminf(a3, b0)), a4));
    float m5 = fmaxf(fmaxf(fmaxf(b5, fminf(a0, b4)), fmaxf(fminf(a1, b3), fminf(a2, b2))),
                     fmaxf(fmaxf(fminf(a3, b1), fminf(a4, b0)), a5));
    a0 = m0; a1 = m1; a2 = m2; a3 = m3; a4 = m4; a5 = m5;
}

// One wave (64 lanes) per row of 1024 f32. 4 waves per 256-thread block.
// Row data lives entirely in registers (16 floats/lane) -> single HBM read.
__global__ __launch_bounds__(256) void sparse_attn_topk_kernel(
        const float* __restrict__ in, float* __restrict__ out, int rows) {
    const int wave = threadIdx.x >> 6;
    const int lane = threadIdx.x & 63;
    const long long row = (long long)blockIdx.x * 4 + wave;
    if (row >= rows) return;

    const float4* rp = (const float4*)(in + row * 1024);
    float4* wp = (float4*)(out + row * 1024);

    // Coalesced: lane i reads float4 at (i + k*64).
    float4 x0 = rp[lane];
    float4 x1 = rp[lane + 64];
    float4 x2 = rp[lane + 128];
    float4 x3 = rp[lane + 192];

    // Per-lane sorted top-6 of its 16 elements.
    float t0 = NEG_INF, t1 = NEG_INF, t2 = NEG_INF,
          t3 = NEG_INF, t4 = NEG_INF, t5 = NEG_INF;
    ins6(x0.x, t0, t1, t2, t3, t4, t5);
    ins6(x0.y, t0, t1, t2, t3, t4, t5);
    ins6(x0.z, t0, t1, t2, t3, t4, t5);
    ins6(x0.w, t0, t1, t2, t3, t4, t5);
    ins6(x1.x, t0, t1, t2, t3, t4, t5);
    ins6(x1.y, t0, t1, t2, t3, t4, t5);
    ins6(x1.z, t0, t1, t2, t3, t4, t5);
    ins6(x1.w, t0, t1, t2, t3, t4, t5);
    ins6(x2.x, t0, t1, t2, t3, t4, t5);
    ins6(x2.y, t0, t1, t2, t3, t4, t5);
    ins6(x2.z, t0, t1, t2, t3, t4, t5);
    ins6(x2.w, t0, t1, t2, t3, t4, t5);
    ins6(x3.x, t0, t1, t2, t3, t4, t5);
    ins6(x3.y, t0, t1, t2, t3, t4, t5);
    ins6(x3.z, t0, t1, t2, t3, t4, t5);
    ins6(x3.w, t0, t1, t2, t3, t4, t5);

    // Wave-wide butterfly merge: all 64 lanes converge to the row's top-6.
    merge6(1,  t0, t1, t2, t3, t4, t5);
    merge6(2,  t0, t1, t2, t3, t4, t5);
    merge6(4,  t0, t1, t2, t3, t4, t5);
    merge6(8,  t0, t1, t2, t3, t4, t5);
    merge6(16, t0, t1, t2, t3, t4, t5);
    merge6(32, t0, t1, t2, t3, t4, t5);

    const float delta = t5 + TKEPS;  // 6th largest + eps

    // Phase 2 from registers: w = max(x - delta, 0), accumulate sum.
    float4 w0, w1, w2, w3;
    float s = 0.0f;
    w0.x = fmaxf(x0.x - delta, 0.0f); s += w0.x;
    w0.y = fmaxf(x0.y - delta, 0.0f); s += w0.y;
    w0.z = fmaxf(x0.z - delta, 0.0f); s += w0.z;
    w0.w = fmaxf(x0.w - delta, 0.0f); s += w0.w;
    w1.x = fmaxf(x1.x - delta, 0.0f); s += w1.x;
    w1.y = fmaxf(x1.y - delta, 0.0f); s += w1.y;
    w1.z = fmaxf(x1.z - delta, 0.0f); s += w1.z;
    w1.w = fmaxf(x1.w - delta, 0.0f); s += w1.w;
    w2.x = fmaxf(x2.x - delta, 0.0f); s += w2.x;
    w2.y = fmaxf(x2.y - delta, 0.0f); s += w2.y;
    w2.z = fmaxf(x2.z - delta, 0.0f); s += w2.z;
    w2.w = fmaxf(x2.w - delta, 0.0f); s += w2.w;
    w3.x = fmaxf(x3.x - delta, 0.0f); s += w3.x;
    w3.y = fmaxf(x3.y - delta, 0.0f); s += w3.y;
    w3.z = fmaxf(x3.z - delta, 0.0f); s += w3.z;
    w3.w = fmaxf(x3.w - delta, 0.0f); s += w3.w;

    // Wave sum reduction.
    s += __shfl_xor(s, 1, 64);
    s += __shfl_xor(s, 2, 64);
    s += __shfl_xor(s, 4, 64);
    s += __shfl_xor(s, 8, 64);
    s += __shfl_xor(s, 16, 64);
    s += __shfl_xor(s, 32, 64);

    const float inv = 1.0f / (s + TKEPS);

    w0.x *= inv; w0.y *= inv; w0.z *= inv; w0.w *= inv;
    w1.x *= inv; w1.y *= inv; w1.z *= inv; w1.w *= inv;
    w2.x *= inv; w2.y *= inv; w2.z *= inv; w2.w *= inv;
    w3.x *= inv; w3.y *= inv; w3.z *= inv; w3.w *= inv;

    wp[lane]       = w0;
    wp[lane + 64]  = w1;
    wp[lane + 128] = w2;
    wp[lane + 192] = w3;
}

extern "C" void kernel_launch(void* const* d_in, const int* in_sizes, int n_in,
                              void* d_out, int out_size, void* d_ws, size_t ws_size,
                              hipStream_t stream) {
    const float* in = (const float*)d_in[0];
    float* out = (float*)d_out;
    const int rows = in_sizes[0] / 1024;           // 65536
    const int blocks = (rows + 3) / 4;             // 4 rows (waves) per block
    sparse_attn_topk_kernel<<<blocks, 256, 0, stream>>>(in, out, rows);
}

// Round 3
// 89.132 us; speedup vs baseline: 1.1202x; 1.1202x over previous
//
#include <hip/hip_runtime.h>
#include <math.h>

#define TKEPS 1e-7f

// Native clang vector type: __builtin_nontemporal_load/store requires a
// pointer to a scalar or clang vector (HIP's float4 class is rejected).
typedef float f32x4 __attribute__((ext_vector_type(4)));

// compare-exchange: hi=max, lo=min
__device__ __forceinline__ void ce(float& hi, float& lo) {
    float m = fmaxf(hi, lo);
    lo = fminf(hi, lo);
    hi = m;
}

// full descending sort of 4 (5 CEs, depth 3)
__device__ __forceinline__ void sort4(float& a, float& b, float& c, float& d) {
    ce(a, b); ce(c, d);
    ce(a, c); ce(b, d);
    ce(b, c);
}

// merge two sorted-desc 4-lists -> sorted-desc top-6 of the union.
// m_i = max over j+l=i+1 of min(a_{j-1}, b_{l-1}) (pure terms a_i/b_i included).
__device__ __forceinline__ void merge44(float a0, float a1, float a2, float a3,
                                        float b0, float b1, float b2, float b3,
                                        float& m0, float& m1, float& m2,
                                        float& m3, float& m4, float& m5) {
    m0 = fmaxf(a0, b0);
    m1 = fmaxf(fmaxf(a1, b1), fminf(a0, b0));
    m2 = fmaxf(fmaxf(a2, b2), fmaxf(fminf(a0, b1), fminf(a1, b0)));
    m3 = fmaxf(fmaxf(a3, b3),
               fmaxf(fmaxf(fminf(a0, b2), fminf(a1, b1)), fminf(a2, b0)));
    m4 = fmaxf(fmaxf(fminf(a0, b3), fminf(a1, b2)),
               fmaxf(fminf(a2, b1), fminf(a3, b0)));
    m5 = fmaxf(fmaxf(fminf(a1, b3), fminf(a2, b2)), fminf(a3, b1));
}

// merge two sorted-desc 6-lists -> sorted-desc top-6 of the union (in-place in a).
__device__ __forceinline__ void merge66(float& a0, float& a1, float& a2,
                                        float& a3, float& a4, float& a5,
                                        float b0, float b1, float b2,
                                        float b3, float b4, float b5) {
    float m0 = fmaxf(a0, b0);
    float m1 = fmaxf(fmaxf(b1, fminf(a0, b0)), a1);
    float m2 = fmaxf(fmaxf(b2, fminf(a0, b1)),
                     fmaxf(fminf(a1, b0), a2));
    float m3 = fmaxf(fmaxf(fmaxf(b3, fminf(a0, b2)), fminf(a1, b1)),
                     fmaxf(fminf(a2, b0), a3));
    float m4 = fmaxf(fmaxf(fmaxf(b4, fminf(a0, b3)), fminf(a1, b2)),
                     fmaxf(fmaxf(fminf(a2, b1), fminf(a3, b0)), a4));
    float m5 = fmaxf(fmaxf(fmaxf(b5, fminf(a0, b4)), fmaxf(fminf(a1, b3), fminf(a2, b2))),
                     fmaxf(fmaxf(fminf(a3, b1), fminf(a4, b0)), a5));
    a0 = m0; a1 = m1; a2 = m2; a3 = m3; a4 = m4; a5 = m5;
}

// butterfly-exchange merge with partner lane (xor mask)
__device__ __forceinline__ void merge6_shfl(int mask, float& a0, float& a1, float& a2,
                                            float& a3, float& a4, float& a5) {
    float b0 = __shfl_xor(a0, mask, 64);
    float b1 = __shfl_xor(a1, mask, 64);
    float b2 = __shfl_xor(a2, mask, 64);
    float b3 = __shfl_xor(a3, mask, 64);
    float b4 = __shfl_xor(a4, mask, 64);
    float b5 = __shfl_xor(a5, mask, 64);
    merge66(a0, a1, a2, a3, a4, a5, b0, b1, b2, b3, b4, b5);
}

// One wave (64 lanes) per row of 1024 f32. 4 waves per 256-thread block.
// Row lives entirely in registers (16 floats/lane) -> single HBM read.
// Nontemporal loads/stores: zero reuse, stream past L2/L3.
__global__ __launch_bounds__(256) void sparse_attn_topk_kernel(
        const float* __restrict__ in, float* __restrict__ out, int rows) {
    const int wave = threadIdx.x >> 6;
    const int lane = threadIdx.x & 63;
    const long long row = (long long)blockIdx.x * 4 + wave;
    if (row >= rows) return;

    const f32x4* rp = (const f32x4*)(in + row * 1024);
    f32x4* wp = (f32x4*)(out + row * 1024);

    // Coalesced: lane i reads 16B at (i + k*64).
    f32x4 x0 = __builtin_nontemporal_load(rp + lane);
    f32x4 x1 = __builtin_nontemporal_load(rp + lane + 64);
    f32x4 x2 = __builtin_nontemporal_load(rp + lane + 128);
    f32x4 x3 = __builtin_nontemporal_load(rp + lane + 192);

    // --- per-lane top-6 of 16 elements, tournament (ILP-friendly) ---
    // 4 independent sort-4s
    float s00 = x0.x, s01 = x0.y, s02 = x0.z, s03 = x0.w;
    float s10 = x1.x, s11 = x1.y, s12 = x1.z, s13 = x1.w;
    float s20 = x2.x, s21 = x2.y, s22 = x2.z, s23 = x2.w;
    float s30 = x3.x, s31 = x3.y, s32 = x3.z, s33 = x3.w;
    sort4(s00, s01, s02, s03);
    sort4(s10, s11, s12, s13);
    sort4(s20, s21, s22, s23);
    sort4(s30, s31, s32, s33);

    // 2 independent merge(4,4) -> top-6
    float p0, p1, p2, p3, p4, p5;
    float q0, q1, q2, q3, q4, q5;
    merge44(s00, s01, s02, s03, s10, s11, s12, s13, p0, p1, p2, p3, p4, p5);
    merge44(s20, s21, s22, s23, s30, s31, s32, s33, q0, q1, q2, q3, q4, q5);

    // merge(6,6) -> per-lane top-6
    merge66(p0, p1, p2, p3, p4, p5, q0, q1, q2, q3, q4, q5);

    // --- wave-wide butterfly: all 64 lanes converge to row top-6 ---
    merge6_shfl(1,  p0, p1, p2, p3, p4, p5);
    merge6_shfl(2,  p0, p1, p2, p3, p4, p5);
    merge6_shfl(4,  p0, p1, p2, p3, p4, p5);
    merge6_shfl(8,  p0, p1, p2, p3, p4, p5);
    merge6_shfl(16, p0, p1, p2, p3, p4, p5);
    merge6_shfl(32, p0, p1, p2, p3, p4, p5);

    const float delta = p5 + TKEPS;  // 6th largest + eps

    // --- phase 2 from registers: w = max(x - delta, 0), accumulate sum ---
    f32x4 w0, w1, w2, w3;
    float s = 0.0f;
    w0.x = fmaxf(x0.x - delta, 0.0f); s += w0.x;
    w0.y = fmaxf(x0.y - delta, 0.0f); s += w0.y;
    w0.z = fmaxf(x0.z - delta, 0.0f); s += w0.z;
    w0.w = fmaxf(x0.w - delta, 0.0f); s += w0.w;
    w1.x = fmaxf(x1.x - delta, 0.0f); s += w1.x;
    w1.y = fmaxf(x1.y - delta, 0.0f); s += w1.y;
    w1.z = fmaxf(x1.z - delta, 0.0f); s += w1.z;
    w1.w = fmaxf(x1.w - delta, 0.0f); s += w1.w;
    w2.x = fmaxf(x2.x - delta, 0.0f); s += w2.x;
    w2.y = fmaxf(x2.y - delta, 0.0f); s += w2.y;
    w2.z = fmaxf(x2.z - delta, 0.0f); s += w2.z;
    w2.w = fmaxf(x2.w - delta, 0.0f); s += w2.w;
    w3.x = fmaxf(x3.x - delta, 0.0f); s += w3.x;
    w3.y = fmaxf(x3.y - delta, 0.0f); s += w3.y;
    w3.z = fmaxf(x3.z - delta, 0.0f); s += w3.z;
    w3.w = fmaxf(x3.w - delta, 0.0f); s += w3.w;

    // wave sum reduction
    s += __shfl_xor(s, 1, 64);
    s += __shfl_xor(s, 2, 64);
    s += __shfl_xor(s, 4, 64);
    s += __shfl_xor(s, 8, 64);
    s += __shfl_xor(s, 16, 64);
    s += __shfl_xor(s, 32, 64);

    const float inv = 1.0f / (s + TKEPS);

    w0.x *= inv; w0.y *= inv; w0.z *= inv; w0.w *= inv;
    w1.x *= inv; w1.y *= inv; w1.z *= inv; w1.w *= inv;
    w2.x *= inv; w2.y *= inv; w2.z *= inv; w2.w *= inv;
    w3.x *= inv; w3.y *= inv; w3.z *= inv; w3.w *= inv;

    __builtin_nontemporal_store(w0, wp + lane);
    __builtin_nontemporal_store(w1, wp + lane + 64);
    __builtin_nontemporal_store(w2, wp + lane + 128);
    __builtin_nontemporal_store(w3, wp + lane + 192);
}

extern "C" void kernel_launch(void* const* d_in, const int* in_sizes, int n_in,
                              void* d_out, int out_size, void* d_ws, size_t ws_size,
                              hipStream_t stream) {
    const float* in = (const float*)d_in[0];
    float* out = (float*)d_out;
    const int rows = in_sizes[0] / 1024;           // 65536
    const int blocks = (rows + 3) / 4;             // 4 rows (waves) per block
    sparse_attn_topk_kernel<<<blocks, 256, 0, stream>>>(in, out, rows);
}